// Round 12
// baseline (1832.020 us; speedup 1.0000x reference)
//
#include <hip/hip_runtime.h>
#include <hip/hip_bf16.h>

typedef __attribute__((ext_vector_type(8))) short bf16x8;
typedef __attribute__((ext_vector_type(4))) float f32x4;
typedef __attribute__((ext_vector_type(4))) unsigned u32x4;
typedef __attribute__((ext_vector_type(2))) unsigned u32x2;

#define SEQT 2048
#define BATCH 32
#define INDIM 512
#define EMB 256
#define HHX 128
#define LBL 16
#define LOG2E 1.44269504f

__device__ __forceinline__ unsigned short f2bf(float f) {
    unsigned u = __float_as_uint(f);
    u += 0x7FFFu + ((u >> 16) & 1u);
    return (unsigned short)(u >> 16);
}
#define BLO(u) __uint_as_float((u) << 16)
#define BHI(u) __uint_as_float((u) & 0xffff0000u)

// Fused-denominator cell: 5 exp2 + 2 rcp. Inputs pre-scaled (-LOG2E for i,f,o;
// +2*LOG2E for g). Clamps keep every factor finite -> NaN-proof saturation.
__device__ __forceinline__ float cell(float ig, float fg, float gg, float og, float& c) {
    float Ef = __builtin_amdgcn_exp2f(fminf(fg, 30.f));
    float Ei = __builtin_amdgcn_exp2f(fminf(ig, 30.f));
    float Eg = __builtin_amdgcn_exp2f(fminf(gg, 60.f));
    float Eo = __builtin_amdgcn_exp2f(fminf(og, 30.f));
    float pf = 1.f + Ef;
    float t1 = (Eg + 1.f) * (1.f + Ei);
    float num = c * t1 + (Eg - 1.f) * pf;
    float cn = num * __builtin_amdgcn_rcpf(pf * t1);
    c = cn;
    float E2 = __builtin_amdgcn_exp2f(fminf(2.f * LOG2E * cn, 60.f));
    float r3 = __builtin_amdgcn_rcpf((E2 + 1.f) * (1.f + Eo));
    return (E2 - 1.f) * r3;
}

// Gate-row permutation: g' = w*64 + q*16 + r  <->  orig = q*128 + w*16 + r
// q = gate (0=i,1=f,2=g,3=o)
__device__ __forceinline__ int orig_of(int gp) {
    return ((gp >> 4) & 3) * 128 + (gp >> 6) * 16 + (gp & 15);
}
__device__ __forceinline__ float gate_scale(int gp) {
    return (((gp >> 4) & 3) == 2) ? (2.f * LOG2E) : (-LOG2E);
}

// ---------------- prep: combined W (Wih @ in_W) + bias, permuted+scaled rows ----------------
__global__ __launch_bounds__(256) void k_prep_wc(
    const float* __restrict__ in_W, const float* __restrict__ in_b,
    const float* __restrict__ Wih_f, const float* __restrict__ b_f,
    const float* __restrict__ Wih_b, const float* __restrict__ b_b,
    unsigned short* __restrict__ Wc, float* __restrict__ bc)
{
    int G0 = blockIdx.x * 8;         // 128 blocks
    int tid = threadIdx.x;
    __shared__ float wrow[8][EMB];
    for (int e = tid; e < 8 * EMB; e += 256) {
        int r = e >> 8, ee = e & 255;
        int G = G0 + r, dir = G >> 9, gp = G & 511;
        wrow[r][ee] = (dir ? Wih_b : Wih_f)[orig_of(gp) * EMB + ee] * gate_scale(gp);
    }
    __syncthreads();
    for (int k = tid; k < INDIM; k += 256) {
        float acc[8] = {0, 0, 0, 0, 0, 0, 0, 0};
        #pragma unroll 4
        for (int e = 0; e < EMB; ++e) {
            float x = in_W[e * INDIM + k];
            #pragma unroll
            for (int r = 0; r < 8; ++r) acc[r] += wrow[r][e] * x;
        }
        #pragma unroll
        for (int r = 0; r < 8; ++r) Wc[(size_t)(G0 + r) * INDIM + k] = f2bf(acc[r]);
    }
    if (tid < 64) {
        for (int r = 0; r < 8; ++r) {
            float p = 0.f;
            for (int e = tid; e < EMB; e += 64) p += wrow[r][e] * in_b[e];
            for (int off = 32; off; off >>= 1) p += __shfl_xor(p, off);
            if (tid == 0) {
                int G = G0 + r, dir = G >> 9, gp = G & 511;
                bc[G] = (dir ? b_b : b_f)[orig_of(gp)] * gate_scale(gp) + p;
            }
        }
    }
}

// ---------------- prep: bf16 converts (Whh permuted+scaled, out_W) ----------------
__global__ __launch_bounds__(256) void k_prep_misc(
    const float* __restrict__ Whh_f, const float* __restrict__ Whh_b,
    const float* __restrict__ out_W,
    unsigned short* __restrict__ Whh_bf, unsigned short* __restrict__ outW_bf)
{
    int idx = blockIdx.x * 256 + threadIdx.x;
    int stride = gridDim.x * 256;
    for (int i = idx; i < 1024 * HHX; i += stride) {
        int G = i >> 7, k = i & 127;
        int dir = G >> 9, gp = G & 511;
        const float* Whh = dir ? Whh_b : Whh_f;
        Whh_bf[i] = f2bf(Whh[orig_of(gp) * HHX + k] * gate_scale(gp));
    }
    for (int i = idx; i < LBL * 256; i += stride) outW_bf[i] = f2bf(out_W[i]);
}

// ---------------- big GEMM: P2 = S @ Wc^T + bc ----------------
// P2 frame layout: frame = (t*2 + dir)*8 + bq (4KB each); within frame:
// [unit u(128)][lb(4)][gate q(4)] bf16 -> lstm thread (w,lq,lr) reads 8B at
// elem ((w*16+lr)*4 + lq)*4, wave-coalesced. Epilogue goes through an LDS
// bounce so the global stores are 4x dwordx4 per thread (fully coalesced).
__global__ __launch_bounds__(512) void k_gemm_p(
    const float* __restrict__ S, const unsigned short* __restrict__ Wc,
    const float* __restrict__ bc, unsigned short* __restrict__ P2)
{
    int m0 = blockIdx.y * 64;
    int n0 = blockIdx.x * 256;
    int tid = threadIdx.x;
    int w = tid >> 6, l = tid & 63;
    int lr = l & 15, lq = l >> 4;
    int wm = w >> 2, wn = w & 3;

    __shared__ __align__(16) unsigned short Alds[64 * 64];
    __shared__ __align__(16) unsigned short Blds[256 * 64];   // also the 32KB bounce buffer

    const f32x4 fzero = {0.f, 0.f, 0.f, 0.f};
    f32x4 acc[2][4];
    #pragma unroll
    for (int a = 0; a < 2; ++a)
        #pragma unroll
        for (int b = 0; b < 4; ++b) acc[a][b] = fzero;

    for (int kt = 0; kt < 8; ++kt) {
        { // stage A (convert fp32->bf16 via cvt_pk, XOR-swizzled rows of 128B)
            int r = tid >> 3, c = tid & 7;
            const float* src = S + (size_t)(m0 + r) * INDIM + kt * 64 + c * 8;
            float4 v0 = *(const float4*)src;
            float4 v1 = *(const float4*)(src + 4);
            unsigned g0, g1, g2, g3;
            asm("v_cvt_pk_bf16_f32 %0, %1, %2" : "=v"(g0) : "v"(v0.x), "v"(v0.y));
            asm("v_cvt_pk_bf16_f32 %0, %1, %2" : "=v"(g1) : "v"(v0.z), "v"(v0.w));
            asm("v_cvt_pk_bf16_f32 %0, %1, %2" : "=v"(g2) : "v"(v1.x), "v"(v1.y));
            asm("v_cvt_pk_bf16_f32 %0, %1, %2" : "=v"(g3) : "v"(v1.z), "v"(v1.w));
            u32x4 wv = {g0, g1, g2, g3};
            *(u32x4*)((char*)Alds + r * 128 + ((c * 16) ^ ((r & 7) << 4))) = wv;
        }
        { // stage B
            int r = tid >> 1, h = tid & 1;
            const unsigned short* bs = Wc + (size_t)(n0 + r) * INDIM + kt * 64;
            #pragma unroll
            for (int cc = 0; cc < 4; ++cc) {
                int ch = h * 4 + cc;
                bf16x8 v = *(const bf16x8*)(bs + ch * 8);
                *(bf16x8*)((char*)Blds + r * 128 + ((ch * 16) ^ ((r & 7) << 4))) = v;
            }
        }
        __syncthreads();
        bf16x8 af[2][2], bfv[4][2];
        #pragma unroll
        for (int tm = 0; tm < 2; ++tm)
            #pragma unroll
            for (int kk = 0; kk < 2; ++kk) {
                int ra = wm * 32 + tm * 16 + lr;
                af[tm][kk] = *(const bf16x8*)((char*)Alds + ra * 128 + ((kk * 64 + lq * 16) ^ ((ra & 7) << 4)));
            }
        #pragma unroll
        for (int tn = 0; tn < 4; ++tn)
            #pragma unroll
            for (int kk = 0; kk < 2; ++kk) {
                int rb = wn * 64 + tn * 16 + lr;
                bfv[tn][kk] = *(const bf16x8*)((char*)Blds + rb * 128 + ((kk * 64 + lq * 16) ^ ((rb & 7) << 4)));
            }
        #pragma unroll
        for (int tm = 0; tm < 2; ++tm)
            #pragma unroll
            for (int tn = 0; tn < 4; ++tn)
                #pragma unroll
                for (int kk = 0; kk < 2; ++kk)
                    acc[tm][tn] = __builtin_amdgcn_mfma_f32_16x16x32_bf16(af[tm][kk], bfv[tn][kk], acc[tm][tn], 0, 0, 0);
        __syncthreads();
    }
    // ---- epilogue via LDS bounce ----
    // value (m, n): m = m0 + wm*32 + tm*16 + lq*4 + j -> t = by*2+wm, bq = tm*4+lq, lb = j
    //               n -> w2 = (bx&1)*4+wn, q = tn, u_lr = lr
    // bounce layout: [fl = wm*8+tm*4+lq (16 frames)][2KB: wn*512 + lr*32 + j*8 + tn*2]
    char* bounce = (char*)Blds;
    {
        float b4[4];
        #pragma unroll
        for (int tn = 0; tn < 4; ++tn) b4[tn] = bc[n0 + wn * 64 + tn * 16 + lr];
        int wbyte = wn * 512 + lr * 32;
        #pragma unroll
        for (int tm = 0; tm < 2; ++tm) {
            #pragma unroll
            for (int j = 0; j < 4; ++j) {
                float f0 = acc[tm][0][j] + b4[0], f1 = acc[tm][1][j] + b4[1];
                float f2 = acc[tm][2][j] + b4[2], f3 = acc[tm][3][j] + b4[3];
                unsigned pA, pB;
                asm("v_cvt_pk_bf16_f32 %0, %1, %2" : "=v"(pA) : "v"(f0), "v"(f1));
                asm("v_cvt_pk_bf16_f32 %0, %1, %2" : "=v"(pB) : "v"(f2), "v"(f3));
                *(u32x2*)(bounce + (wm * 8 + tm * 4 + lq) * 2048 + wbyte + j * 8) = (u32x2){pA, pB};
            }
        }
    }
    __syncthreads();
    { // readout: thread handles 64B, coalesced dwordx4 stores
        int dirg = blockIdx.x >> 1;
        int halfoff = (blockIdx.x & 1) * 2048;
        #pragma unroll
        for (int s = 0; s < 4; ++s) {
            int idx = tid * 4 + s;               // 16B chunk index (0..2047)
            int fl = idx >> 7, infr = (idx & 127) * 16;
            int t = blockIdx.y * 2 + (fl >> 3), bq = fl & 7;
            u32x4 v = *(u32x4*)(bounce + idx * 16);
            char* dst = (char*)P2 + ((size_t)((t * 2 + dirg) * 8 + bq)) * 4096 + halfoff + infr;
            *(u32x4*)dst = v;
        }
    }
}

// ---------------- LSTM recurrence: 16 blocks (dir x 8 batch-quads of 4), 512 threads ----------------
// Batches live in A rows rowOf(b) = b*4 = {0,4,8,12}; other rows zero. Every lane's
// C row lq*4+0 is its single cell (batch lq, unit w*16+lr) -- no cross-lane traffic.
__global__ __launch_bounds__(512) void k_lstm(
    const unsigned short* __restrict__ P2, const unsigned short* __restrict__ Whh_bf,
    const float* __restrict__ h0, const float* __restrict__ c0,
    unsigned short* __restrict__ H)
{
    int blk = blockIdx.x;
    int dir = blk >> 3, bq = blk & 7;
    int tid = threadIdx.x;
    int w = tid >> 6, l = tid & 63;
    int lr = l & 15, lq = l >> 4;

    __shared__ __align__(16) unsigned short hbuf[2][16 * 128];
    char* hb = (char*)hbuf;

    // Whh fragments: wave w owns gates q=0..3 of units [w*16, w*16+16)
    bf16x8 bfrag[4][4];
    #pragma unroll
    for (int q = 0; q < 4; ++q)
        #pragma unroll
        for (int ko = 0; ko < 4; ++ko) {
            int row = dir * 512 + w * 64 + q * 16 + lr;
            bfrag[q][ko] = *(const bf16x8*)(Whh_bf + (size_t)row * HHX + ko * 32 + lq * 8);
        }

    int u = w * 16 + lr;
    float cA = c0[(dir * 32 + bq * 4 + lq) * HHX + u];

    // stage h0: batch b -> row b*4; other rows zero; buf1 zeroed
    for (int e = tid; e < 2048; e += 512) {
        int r = e >> 7, uu = e & 127;
        unsigned short v = 0;
        if ((r & 3) == 0) {
            int b = r >> 2;
            v = f2bf(h0[(dir * 32 + bq * 4 + b) * HHX + uu]);
        }
        int addr = (r * 256 + uu * 2) ^ ((r & 7) << 4);
        *(unsigned short*)(hb + addr) = v;
        *(unsigned short*)(hb + 4096 + addr) = 0;
    }
    __syncthreads();

    // loop-invariant LDS offsets
    const int rd0 = (lr * 256 + 0 * 64 + lq * 16) ^ ((lr & 7) << 4);
    const int rd1 = (lr * 256 + 1 * 64 + lq * 16) ^ ((lr & 7) << 4);
    const int rd2 = (lr * 256 + 2 * 64 + lq * 16) ^ ((lr & 7) << 4);
    const int rd3 = (lr * 256 + 3 * 64 + lq * 16) ^ ((lr & 7) << 4);
    const int rA = lq * 4;
    const int waA = (rA * 256 + u * 2) ^ ((rA & 7) << 4);

    int t0 = dir ? (SEQT - 1) : 0;
    const long long pstep = (dir ? -1LL : 1LL) * (2LL * 8 * 2048);
    const unsigned short* pptr = P2 + ((size_t)(t0 * 2 + dir) * 8 + bq) * 2048 + ((size_t)u * 4 + lq) * 4;
    u32x2 pc = *(const u32x2*)pptr;
    pptr += pstep;

    unsigned short* hpA = H + ((size_t)t0 * 32 + bq * 4 + lq) * 256 + dir * 128 + u;
    const long long hstep = (dir ? -1LL : 1LL) * (32 * 256);

// LDS-only barrier: order the h exchange without draining vmcnt (P prefetch +
// H stores stay in flight across steps).
#define LBAR() asm volatile("s_waitcnt lgkmcnt(0)\n\ts_barrier" ::: "memory")

#define STEP(CUR, PF) do { \
    bf16x8 af0 = *(const bf16x8*)(hb + (CUR) * 4096 + rd0); \
    bf16x8 af1 = *(const bf16x8*)(hb + (CUR) * 4096 + rd1); \
    bf16x8 af2 = *(const bf16x8*)(hb + (CUR) * 4096 + rd2); \
    bf16x8 af3 = *(const bf16x8*)(hb + (CUR) * 4096 + rd3); \
    u32x2 u0 = pc; \
    if (PF) { pc = *(const u32x2*)pptr; pptr += pstep; } \
    f32x4 a0 = {BLO(u0.x), 0.f, 0.f, 0.f}; \
    f32x4 a1 = {BHI(u0.x), 0.f, 0.f, 0.f}; \
    f32x4 a2 = {BLO(u0.y), 0.f, 0.f, 0.f}; \
    f32x4 a3 = {BHI(u0.y), 0.f, 0.f, 0.f}; \
    a0 = __builtin_amdgcn_mfma_f32_16x16x32_bf16(af0, bfrag[0][0], a0, 0, 0, 0); \
    a0 = __builtin_amdgcn_mfma_f32_16x16x32_bf16(af1, bfrag[0][1], a0, 0, 0, 0); \
    a0 = __builtin_amdgcn_mfma_f32_16x16x32_bf16(af2, bfrag[0][2], a0, 0, 0, 0); \
    a0 = __builtin_amdgcn_mfma_f32_16x16x32_bf16(af3, bfrag[0][3], a0, 0, 0, 0); \
    a1 = __builtin_amdgcn_mfma_f32_16x16x32_bf16(af0, bfrag[1][0], a1, 0, 0, 0); \
    a1 = __builtin_amdgcn_mfma_f32_16x16x32_bf16(af1, bfrag[1][1], a1, 0, 0, 0); \
    a1 = __builtin_amdgcn_mfma_f32_16x16x32_bf16(af2, bfrag[1][2], a1, 0, 0, 0); \
    a1 = __builtin_amdgcn_mfma_f32_16x16x32_bf16(af3, bfrag[1][3], a1, 0, 0, 0); \
    a2 = __builtin_amdgcn_mfma_f32_16x16x32_bf16(af0, bfrag[2][0], a2, 0, 0, 0); \
    a2 = __builtin_amdgcn_mfma_f32_16x16x32_bf16(af1, bfrag[2][1], a2, 0, 0, 0); \
    a2 = __builtin_amdgcn_mfma_f32_16x16x32_bf16(af2, bfrag[2][2], a2, 0, 0, 0); \
    a2 = __builtin_amdgcn_mfma_f32_16x16x32_bf16(af3, bfrag[2][3], a2, 0, 0, 0); \
    a3 = __builtin_amdgcn_mfma_f32_16x16x32_bf16(af0, bfrag[3][0], a3, 0, 0, 0); \
    a3 = __builtin_amdgcn_mfma_f32_16x16x32_bf16(af1, bfrag[3][1], a3, 0, 0, 0); \
    a3 = __builtin_amdgcn_mfma_f32_16x16x32_bf16(af2, bfrag[3][2], a3, 0, 0, 0); \
    a3 = __builtin_amdgcn_mfma_f32_16x16x32_bf16(af3, bfrag[3][3], a3, 0, 0, 0); \
    float hnA = cell(a0[0], a1[0], a2[0], a3[0], cA); \
    unsigned pk; \
    asm("v_cvt_pk_bf16_f32 %0, %1, %2" : "=v"(pk) : "v"(hnA), "v"(hnA)); \
    unsigned short sA = (unsigned short)pk; \
    *(unsigned short*)(hb + (((CUR) ^ 1) * 4096) + waA) = sA; \
    hpA[0] = sA; \
    hpA += hstep; \
    LBAR(); \
} while (0)

    for (int it = 0; it < 1023; ++it) {
        STEP(0, true);
        STEP(1, true);
    }
    STEP(0, true);
    STEP(1, false);
#undef STEP
#undef LBAR
}

// ---------------- feats: F(65536x16) = H @ outW^T + out_b ----------------
__global__ __launch_bounds__(256) void k_feats(
    const unsigned short* __restrict__ H, const unsigned short* __restrict__ outW_bf,
    const float* __restrict__ out_b, float* __restrict__ feats)
{
    int m0 = blockIdx.x * 64;
    int tid = threadIdx.x;
    int w = tid >> 6, l = tid & 63;
    int lr = l & 15, lq = l >> 4;
    __shared__ __align__(16) unsigned short Hl[64 * 256];

    {
        int r = tid >> 2, cb = (tid & 3) * 8;
        #pragma unroll
        for (int cc = 0; cc < 8; ++cc) {
            int c = cb + cc;
            bf16x8 v = *(const bf16x8*)(H + (size_t)(m0 + r) * 256 + c * 8);
            *(bf16x8*)((char*)Hl + r * 512 + ((c * 16) ^ ((r & 7) << 4))) = v;
        }
    }
    bf16x8 bw[8];
    #pragma unroll
    for (int ko = 0; ko < 8; ++ko)
        bw[ko] = *(const bf16x8*)(outW_bf + lr * 256 + ko * 32 + lq * 8);
    __syncthreads();
    int row = w * 16 + lr;
    f32x4 acc = {0.f, 0.f, 0.f, 0.f};
    #pragma unroll
    for (int ko = 0; ko < 8; ++ko) {
        bf16x8 a = *(const bf16x8*)((char*)Hl + row * 512 + ((ko * 64 + lq * 16) ^ ((row & 7) << 4)));
        acc = __builtin_amdgcn_mfma_f32_16x16x32_bf16(a, bw[ko], acc, 0, 0, 0);
    }
    float ob = out_b[lr];
    #pragma unroll
    for (int j = 0; j < 4; ++j) {
        int m = m0 + w * 16 + lq * 4 + j;
        feats[(size_t)m * 16 + lr] = acc[j] + ob;
    }
}

// ---------------- Viterbi: 1 block per batch, 1 wave; DPP reduce + packed backtrack ----------------
template <int CTRL>
__device__ __forceinline__ float dppf(float x) {
    return __int_as_float(__builtin_amdgcn_update_dpp(0, __float_as_int(x), CTRL, 0xF, 0xF, true));
}
template <int CTRL>
__device__ __forceinline__ int dppi(int x) {
    return __builtin_amdgcn_update_dpp(0, x, CTRL, 0xF, 0xF, true);
}

__global__ __launch_bounds__(64) void k_viterbi(
    const float* __restrict__ feats, const float* __restrict__ trans,
    float* __restrict__ out)
{
    int b = blockIdx.x;
    int l = threadIdx.x;
    int i = l >> 2, s = l & 3;          // i = next-label (0..15), s = prev-quad (0..3)
    __shared__ unsigned char bp[SEQT * 16];
    __shared__ __align__(16) float fch[256 * 16];
    __shared__ unsigned long long bp64[SEQT];

    float tr[4];
    #pragma unroll
    for (int m = 0; m < 4; ++m) tr[m] = trans[i * 16 + s * 4 + m];
    float fvloc[4];
    #pragma unroll
    for (int m = 0; m < 4; ++m) fvloc[m] = (s * 4 + m == 0) ? 0.f : -10000.f;

    int ga[4];
    #pragma unroll
    for (int m = 0; m < 4; ++m) ga[m] = (16 * s + 4 * m) * 4;   // bpermute byte addr

    for (int t = 0; t < SEQT; ++t) {
        if ((t & 255) == 0) {
            __syncthreads();
            for (int k = l; k < 256; k += 64) {
                const float4* src = (const float4*)(feats + (size_t)((t + k) * 32 + b) * 16);
                float4 v0 = src[0], v1 = src[1], v2 = src[2], v3 = src[3];
                float4* dst = (float4*)(fch + k * 16);
                dst[0] = v0; dst[1] = v1; dst[2] = v2; dst[3] = v3;
            }
            __syncthreads();
        }
        float best = fvloc[0] + tr[0];
        int bj = s * 4;
        #pragma unroll
        for (int m = 1; m < 4; ++m) {
            float v = fvloc[m] + tr[m];
            if (v > best) { best = v; bj = s * 4 + m; }
        }
        { // quad xor1 via DPP quad_perm [1,0,3,2]
            float ov = dppf<0xB1>(best); int oj = dppi<0xB1>(bj);
            bool take = (ov > best) || (ov == best && oj < bj);
            best = take ? ov : best; bj = take ? oj : bj;
        }
        { // quad xor2 via DPP quad_perm [2,3,0,1]
            float ov = dppf<0x4E>(best); int oj = dppi<0x4E>(bj);
            bool take = (ov > best) || (ov == best && oj < bj);
            best = take ? ov : best; bj = take ? oj : bj;
        }
        float fvn = best + fch[(t & 255) * 16 + i];
        if (s == 0) bp[t * 16 + i] = (unsigned char)bj;
        #pragma unroll
        for (int m = 0; m < 4; ++m)
            fvloc[m] = __int_as_float(__builtin_amdgcn_ds_bpermute(ga[m], __float_as_int(fvn)));
    }
    // termination
    float bestS = fvloc[0] + trans[16 + s * 4];
    int bl = s * 4;
    #pragma unroll
    for (int m = 1; m < 4; ++m) {
        float tv = fvloc[m] + trans[16 + s * 4 + m];
        if (tv > bestS) { bestS = tv; bl = s * 4 + m; }
    }
    {
        float ov = dppf<0xB1>(bestS); int oj = dppi<0xB1>(bl);
        bool take = (ov > bestS) || (ov == bestS && oj < bl);
        bestS = take ? ov : bestS; bl = take ? oj : bl;
    }
    {
        float ov = dppf<0x4E>(bestS); int oj = dppi<0x4E>(bl);
        bool take = (ov > bestS) || (ov == bestS && oj < bl);
        bestS = take ? ov : bestS; bl = take ? oj : bl;
    }
    __syncthreads();
    // pack bp rows into nibble-u64 (address-independent backtrack reads)
    for (int t = l; t < SEQT; t += 64) {
        const uint4* p = (const uint4*)(bp + t * 16);
        uint4 u = *p;
        unsigned n0 = (u.x | (u.x >> 4)) & 0x00FF00FFu; n0 = (n0 | (n0 >> 8)) & 0xFFFFu;
        unsigned n1 = (u.y | (u.y >> 4)) & 0x00FF00FFu; n1 = (n1 | (n1 >> 8)) & 0xFFFFu;
        unsigned n2 = (u.z | (u.z >> 4)) & 0x00FF00FFu; n2 = (n2 | (n2 >> 8)) & 0xFFFFu;
        unsigned n3 = (u.w | (u.w >> 4)) & 0x00FF00FFu; n3 = (n3 | (n3 >> 8)) & 0xFFFFu;
        bp64[t] = (unsigned long long)n0 | ((unsigned long long)n1 << 16)
                | ((unsigned long long)n2 << 32) | ((unsigned long long)n3 << 48);
    }
    __syncthreads();
    if (l == 0) out[b] = bestS;
    // all lanes run the chain redundantly; lane t&63 stores t
    int lbl = bl;
    #pragma unroll 8
    for (int t = SEQT - 1; t >= 0; --t) {
        if ((t & 63) == l) out[32 + (size_t)t * 32 + b] = (float)lbl;
        lbl = (int)((bp64[t] >> (lbl * 4)) & 15ull);
    }
}

extern "C" void kernel_launch(void* const* d_in, const int* in_sizes, int n_in,
                              void* d_out, int out_size, void* d_ws, size_t ws_size,
                              hipStream_t stream) {
    const float* source = (const float*)d_in[0];
    const float* in_W  = (const float*)d_in[1];
    const float* in_b  = (const float*)d_in[2];
    const float* Wih_f = (const float*)d_in[3];
    const float* Whh_f = (const float*)d_in[4];
    const float* b_f   = (const float*)d_in[5];
    const float* Wih_b = (const float*)d_in[6];
    const float* Whh_b = (const float*)d_in[7];
    const float* b_b   = (const float*)d_in[8];
    const float* out_W = (const float*)d_in[9];
    const float* out_b = (const float*)d_in[10];
    const float* trans = (const float*)d_in[11];
    const float* h0    = (const float*)d_in[12];
    const float* c0    = (const float*)d_in[13];
    float* out = (float*)d_out;

    char* ws = (char*)d_ws;
    unsigned short* P2      = (unsigned short*)(ws);                 // 32768 frames * 4KB = 134217728
    unsigned short* H       = (unsigned short*)(ws + 134217728);     // 65536*256*2  =  33554432
    float*          feats   = (float*)         (ws + 167772160);     // 65536*16*4   =   4194304
    unsigned short* Wc      = (unsigned short*)(ws + 171966464);     // 1024*512*2   =   1048576
    float*          bc      = (float*)         (ws + 173015040);     // 1024*4
    unsigned short* Whh_bf  = (unsigned short*)(ws + 173019136);     // 1024*128*2   =    262144
    unsigned short* outW_bf = (unsigned short*)(ws + 173281280);     // 16*256*2
    // total ~173.3 MB

    hipLaunchKernelGGL(k_prep_wc, dim3(128), dim3(256), 0, stream,
                       in_W, in_b, Wih_f, b_f, Wih_b, b_b, Wc, bc);
    hipLaunchKernelGGL(k_prep_misc, dim3(256), dim3(256), 0, stream,
                       Whh_f, Whh_b, out_W, Whh_bf, outW_bf);
    hipLaunchKernelGGL(k_gemm_p, dim3(4, 1024), dim3(512), 0, stream,
                       source, Wc, bc, P2);
    hipLaunchKernelGGL(k_lstm, dim3(16), dim3(512), 0, stream,
                       P2, Whh_bf, h0, c0, H);
    hipLaunchKernelGGL(k_feats, dim3(1024), dim3(256), 0, stream,
                       H, outW_bf, out_b, feats);
    hipLaunchKernelGGL(k_viterbi, dim3(32), dim3(64), 0, stream,
                       feats, trans, out);
}